// Round 1
// baseline (176.061 us; speedup 1.0000x reference)
//
#include <hip/hip_runtime.h>

#define NUM_VOXELS 2000000
#define NUM_CLUSTS 2000
#define NUM_EDGES  16000
// accumulator layout in ws: [0,8000) = clust_sum[c*4+f], [8000,10000) = clust_cnt[c]
#define ACC_N 10000

#define A_BLOCKS 256
#define A_THREADS 1024

__device__ __forceinline__ void lds_fadd(float* p, float v) {
    __hip_atomic_fetch_add(p, v, __ATOMIC_RELAXED, __HIP_MEMORY_SCOPE_WORKGROUP);
}

__global__ __launch_bounds__(A_THREADS) void seg_accum(
        const float* __restrict__ data,
        const int* __restrict__ cids,
        float* __restrict__ acc) {
    __shared__ float ls[ACC_N];
    for (int o = threadIdx.x; o < ACC_N; o += A_THREADS) ls[o] = 0.0f;
    __syncthreads();

    const int ngroups = NUM_VOXELS / 4;  // 4 voxels (20 floats = 5 float4) per group
    for (int g = blockIdx.x * A_THREADS + threadIdx.x; g < ngroups;
         g += A_BLOCKS * A_THREADS) {
        const float4* dp = (const float4*)(data + 20ull * (unsigned)g);
        float4 q0 = dp[0];
        float4 q1 = dp[1];
        float4 q2 = dp[2];
        float4 q3 = dp[3];
        float4 q4 = dp[4];
        int4 c4 = *(const int4*)(cids + 4ull * (unsigned)g);

        // voxel 0: flat floats 1..4
        {
            int c = c4.x;
            lds_fadd(&ls[c * 4 + 0], q0.y);
            lds_fadd(&ls[c * 4 + 1], q0.z);
            lds_fadd(&ls[c * 4 + 2], q0.w);
            lds_fadd(&ls[c * 4 + 3], q1.x);
            lds_fadd(&ls[8000 + c], 1.0f);
        }
        // voxel 1: flat floats 6..9
        {
            int c = c4.y;
            lds_fadd(&ls[c * 4 + 0], q1.z);
            lds_fadd(&ls[c * 4 + 1], q1.w);
            lds_fadd(&ls[c * 4 + 2], q2.x);
            lds_fadd(&ls[c * 4 + 3], q2.y);
            lds_fadd(&ls[8000 + c], 1.0f);
        }
        // voxel 2: flat floats 11..14
        {
            int c = c4.z;
            lds_fadd(&ls[c * 4 + 0], q2.w);
            lds_fadd(&ls[c * 4 + 1], q3.x);
            lds_fadd(&ls[c * 4 + 2], q3.y);
            lds_fadd(&ls[c * 4 + 3], q3.z);
            lds_fadd(&ls[8000 + c], 1.0f);
        }
        // voxel 3: flat floats 16..19
        {
            int c = c4.w;
            lds_fadd(&ls[c * 4 + 0], q4.x);
            lds_fadd(&ls[c * 4 + 1], q4.y);
            lds_fadd(&ls[c * 4 + 2], q4.z);
            lds_fadd(&ls[c * 4 + 3], q4.w);
            lds_fadd(&ls[8000 + c], 1.0f);
        }
    }
    __syncthreads();

    for (int o = threadIdx.x; o < ACC_N; o += A_THREADS) {
        // device-scope (agent) f32 atomic add -> hw global_atomic_add_f32
        __hip_atomic_fetch_add(&acc[o], ls[o], __ATOMIC_RELAXED,
                               __HIP_MEMORY_SCOPE_AGENT);
    }
}

#define C_BLOCKS 256
#define C_THREADS 256
#define C_WAVES_TOTAL (C_BLOCKS * (C_THREADS / 64))

__global__ __launch_bounds__(C_THREADS) void edge_mlp(
        const float* __restrict__ acc,
        const int* __restrict__ eidx,
        const float* __restrict__ W1, const float* __restrict__ b1,
        const float* __restrict__ W2, const float* __restrict__ b2,
        float* __restrict__ out) {
    __shared__ float hbuf[C_THREADS / 64][128];
    const int lane = threadIdx.x & 63;
    const int w = threadIdx.x >> 6;
    const int wg = blockIdx.x * (C_THREADS / 64) + w;  // global wave id

    // per-lane weight preload (reused across all edges this wave handles)
    float w1a[4], w1b[4];
#pragma unroll
    for (int c = 0; c < 4; ++c) {
        w1a[c] = W1[c * 128 + lane];
        w1b[c] = W1[c * 128 + 64 + lane];
    }
    const float b1a = b1[lane];
    const float b1b = b1[64 + lane];
    const float b2j = b2[lane];
    // W2 column `lane` in registers: 128 VGPRs, coalesced load, L2-resident
    float w2c[128];
#pragma unroll
    for (int k = 0; k < 128; ++k) w2c[k] = W2[k * 64 + lane];

    for (int e = wg; e < NUM_EDGES; e += C_WAVES_TOTAL) {
        const int e0 = eidx[e];
        const int e1 = eidx[NUM_EDGES + e];
        const float cnt = acc[8000 + e0] + acc[8000 + e1];
        const float rden = 1.0f / fmaxf(cnt, 1.0f);
        const float p0 = (acc[e0 * 4 + 0] + acc[e1 * 4 + 0]) * rden;
        const float p1 = (acc[e0 * 4 + 1] + acc[e1 * 4 + 1]) * rden;
        const float p2 = (acc[e0 * 4 + 2] + acc[e1 * 4 + 2]) * rden;
        const float p3 = (acc[e0 * 4 + 3] + acc[e1 * 4 + 3]) * rden;

        float ha = b1a + p0 * w1a[0] + p1 * w1a[1] + p2 * w1a[2] + p3 * w1a[3];
        float hb = b1b + p0 * w1b[0] + p1 * w1b[1] + p2 * w1b[2] + p3 * w1b[3];
        ha = fmaxf(ha, 0.0f);
        hb = fmaxf(hb, 0.0f);

        // per-wave h exchange through LDS (in-order LDS pipe within a wave;
        // compiler inserts lgkmcnt waits for the aliasing read)
        hbuf[w][lane] = ha;
        hbuf[w][64 + lane] = hb;

        float o0 = b2j;
#pragma unroll
        for (int k = 0; k < 128; k += 4) {
            float4 h4 = *(const float4*)&hbuf[w][k];  // broadcast read
            o0 += h4.x * w2c[k] + h4.y * w2c[k + 1] + h4.z * w2c[k + 2] +
                  h4.w * w2c[k + 3];
        }
        out[(size_t)e * 64 + lane] = o0;
    }
}

extern "C" void kernel_launch(void* const* d_in, const int* in_sizes, int n_in,
                              void* d_out, int out_size, void* d_ws, size_t ws_size,
                              hipStream_t stream) {
    const float* data = (const float*)d_in[0];
    const int* cids   = (const int*)d_in[1];
    const int* eidx   = (const int*)d_in[2];
    const float* W1   = (const float*)d_in[3];
    const float* b1   = (const float*)d_in[4];
    const float* W2   = (const float*)d_in[5];
    const float* b2   = (const float*)d_in[6];
    float* out = (float*)d_out;
    float* acc = (float*)d_ws;

    hipMemsetAsync(acc, 0, ACC_N * sizeof(float), stream);
    seg_accum<<<A_BLOCKS, A_THREADS, 0, stream>>>(data, cids, acc);
    edge_mlp<<<C_BLOCKS, C_THREADS, 0, stream>>>(acc, eidx, W1, b1, W2, b2, out);
}

// Round 2
// 176.057 us; speedup vs baseline: 1.0000x; 1.0000x over previous
//
#include <hip/hip_runtime.h>

#define NUM_VOXELS 2000000
#define NUM_CLUSTS 2000
#define NUM_EDGES  16000

// SoA accumulator: sums at [f*ST + c] (f=0..3), count at [4*ST + c].
// ST=2048: 2048%32==0 so LDS bank = c%32 -> full 32-bank spread for the
// random cluster ids (old layout c*4+f hit only 8 banks -> 8-way atomic conflict).
#define ST   2048
#define ACCN (5 * ST)  // 10240 floats = 40 KiB

#define A_BLOCKS 256
#define A_THREADS 1024

template <bool PARTIAL>
__global__ __launch_bounds__(A_THREADS) void seg_accum(
        const float* __restrict__ data,
        const int* __restrict__ cids,
        float* __restrict__ out) {  // PARTIAL: out = partials base; else: acc (pre-zeroed)
    __shared__ float ls[ACCN];
    for (int o = threadIdx.x; o < ACCN; o += A_THREADS) ls[o] = 0.0f;
    __syncthreads();

    const int ngroups = NUM_VOXELS / 4;  // 4 voxels = 5 float4 + 1 int4 per thread-iter
    for (int g = blockIdx.x * A_THREADS + threadIdx.x; g < ngroups;
         g += A_BLOCKS * A_THREADS) {
        const float4* dp = (const float4*)(data + 20ull * (unsigned)g);
        float4 q0 = dp[0];
        float4 q1 = dp[1];
        float4 q2 = dp[2];
        float4 q3 = dp[3];
        float4 q4 = dp[4];
        int4 c4 = *(const int4*)(cids + 4ull * (unsigned)g);

        // voxel 0: flat floats 1..4
        atomicAdd(&ls[0 * ST + c4.x], q0.y);
        atomicAdd(&ls[1 * ST + c4.x], q0.z);
        atomicAdd(&ls[2 * ST + c4.x], q0.w);
        atomicAdd(&ls[3 * ST + c4.x], q1.x);
        atomicAdd(&ls[4 * ST + c4.x], 1.0f);
        // voxel 1: flat floats 6..9
        atomicAdd(&ls[0 * ST + c4.y], q1.z);
        atomicAdd(&ls[1 * ST + c4.y], q1.w);
        atomicAdd(&ls[2 * ST + c4.y], q2.x);
        atomicAdd(&ls[3 * ST + c4.y], q2.y);
        atomicAdd(&ls[4 * ST + c4.y], 1.0f);
        // voxel 2: flat floats 11..14
        atomicAdd(&ls[0 * ST + c4.z], q2.w);
        atomicAdd(&ls[1 * ST + c4.z], q3.x);
        atomicAdd(&ls[2 * ST + c4.z], q3.y);
        atomicAdd(&ls[3 * ST + c4.z], q3.z);
        atomicAdd(&ls[4 * ST + c4.z], 1.0f);
        // voxel 3: flat floats 16..19
        atomicAdd(&ls[0 * ST + c4.w], q4.x);
        atomicAdd(&ls[1 * ST + c4.w], q4.y);
        atomicAdd(&ls[2 * ST + c4.w], q4.z);
        atomicAdd(&ls[3 * ST + c4.w], q4.w);
        atomicAdd(&ls[4 * ST + c4.w], 1.0f);
    }
    __syncthreads();

    if (PARTIAL) {
        // streaming, coalesced, non-atomic per-block partial dump
        float* p = out + (size_t)blockIdx.x * ACCN;
        for (int o = threadIdx.x; o < ACCN; o += A_THREADS) p[o] = ls[o];
    } else {
        // fallback: device-scope atomic flush into pre-zeroed acc
        for (int o = threadIdx.x; o < ACCN; o += A_THREADS) {
            float v = ls[o];
            if (v != 0.0f)
                __hip_atomic_fetch_add(&out[o], v, __ATOMIC_RELAXED,
                                       __HIP_MEMORY_SCOPE_AGENT);
        }
    }
}

__global__ __launch_bounds__(256) void seg_reduce(
        const float* __restrict__ part, float* __restrict__ acc) {
    const int i = blockIdx.x * 256 + threadIdx.x;
    if (i >= ACCN) return;
    float s0 = 0.f, s1 = 0.f, s2 = 0.f, s3 = 0.f;
    for (int b = 0; b < A_BLOCKS; b += 4) {
        s0 += part[(size_t)(b + 0) * ACCN + i];
        s1 += part[(size_t)(b + 1) * ACCN + i];
        s2 += part[(size_t)(b + 2) * ACCN + i];
        s3 += part[(size_t)(b + 3) * ACCN + i];
    }
    acc[i] = (s0 + s1) + (s2 + s3);
}

#define E_BLOCKS 512
#define E_THREADS 256
#define E_WAVES (E_BLOCKS * (E_THREADS / 64))

__global__ __launch_bounds__(E_THREADS) void edge_mlp(
        const float* __restrict__ acc,
        const int* __restrict__ eidx,
        const float* __restrict__ W1, const float* __restrict__ b1,
        const float* __restrict__ W2, const float* __restrict__ b2,
        float* __restrict__ out) {
    __shared__ float sacc[ACCN];                 // 40 KiB staged accumulators
    __shared__ float hbuf[E_THREADS / 64][128];  // per-wave h exchange
    const int lane = threadIdx.x & 63;
    const int w = threadIdx.x >> 6;
    const int wg = blockIdx.x * (E_THREADS / 64) + w;

    // per-lane weight preload (independent of sacc stage; issued before barrier)
    float w1a[4], w1b[4];
#pragma unroll
    for (int c = 0; c < 4; ++c) {
        w1a[c] = W1[c * 128 + lane];
        w1b[c] = W1[c * 128 + 64 + lane];
    }
    const float b1a = b1[lane];
    const float b1b = b1[64 + lane];
    const float b2j = b2[lane];
    float w2c[128];  // W2 column `lane` in registers (coalesced, L2-resident)
#pragma unroll
    for (int k = 0; k < 128; ++k) w2c[k] = W2[k * 64 + lane];

    for (int o = threadIdx.x; o < ACCN; o += E_THREADS) sacc[o] = acc[o];
    __syncthreads();

    for (int e = wg; e < NUM_EDGES; e += E_WAVES) {
        const int e0 = eidx[e];                // wave-uniform -> scalar loads
        const int e1 = eidx[NUM_EDGES + e];
        // broadcast LDS reads (uniform address, conflict-free)
        const float cnt = sacc[4 * ST + e0] + sacc[4 * ST + e1];
        const float rden = 1.0f / fmaxf(cnt, 1.0f);
        const float p0 = (sacc[0 * ST + e0] + sacc[0 * ST + e1]) * rden;
        const float p1 = (sacc[1 * ST + e0] + sacc[1 * ST + e1]) * rden;
        const float p2 = (sacc[2 * ST + e0] + sacc[2 * ST + e1]) * rden;
        const float p3 = (sacc[3 * ST + e0] + sacc[3 * ST + e1]) * rden;

        float ha = b1a + p0 * w1a[0] + p1 * w1a[1] + p2 * w1a[2] + p3 * w1a[3];
        float hb = b1b + p0 * w1b[0] + p1 * w1b[1] + p2 * w1b[2] + p3 * w1b[3];
        ha = fmaxf(ha, 0.0f);
        hb = fmaxf(hb, 0.0f);

        hbuf[w][lane] = ha;
        hbuf[w][64 + lane] = hb;

        float o0 = b2j;
#pragma unroll
        for (int k = 0; k < 128; k += 4) {
            float4 h4 = *(const float4*)&hbuf[w][k];  // broadcast read
            o0 += h4.x * w2c[k] + h4.y * w2c[k + 1] + h4.z * w2c[k + 2] +
                  h4.w * w2c[k + 3];
        }
        out[(size_t)e * 64 + lane] = o0;  // coalesced 256B per wave
    }
}

extern "C" void kernel_launch(void* const* d_in, const int* in_sizes, int n_in,
                              void* d_out, int out_size, void* d_ws, size_t ws_size,
                              hipStream_t stream) {
    const float* data = (const float*)d_in[0];
    const int* cids   = (const int*)d_in[1];
    const int* eidx   = (const int*)d_in[2];
    const float* W1   = (const float*)d_in[3];
    const float* b1   = (const float*)d_in[4];
    const float* W2   = (const float*)d_in[5];
    const float* b2   = (const float*)d_in[6];
    float* out = (float*)d_out;
    float* ws  = (float*)d_ws;

    const size_t need = (size_t)(A_BLOCKS + 1) * ACCN * sizeof(float);  // ~10.5 MB
    if (ws_size >= need) {
        float* part = ws;
        float* acc = ws + (size_t)A_BLOCKS * ACCN;
        seg_accum<true><<<A_BLOCKS, A_THREADS, 0, stream>>>(data, cids, part);
        seg_reduce<<<(ACCN + 255) / 256, 256, 0, stream>>>(part, acc);
        edge_mlp<<<E_BLOCKS, E_THREADS, 0, stream>>>(acc, eidx, W1, b1, W2, b2, out);
    } else {
        float* acc = ws;
        hipMemsetAsync(acc, 0, ACCN * sizeof(float), stream);
        seg_accum<false><<<A_BLOCKS, A_THREADS, 0, stream>>>(data, cids, acc);
        edge_mlp<<<E_BLOCKS, E_THREADS, 0, stream>>>(acc, eidx, W1, b1, W2, b2, out);
    }
}

// Round 3
// 175.033 us; speedup vs baseline: 1.0059x; 1.0059x over previous
//
#include <hip/hip_runtime.h>

#define NUM_VOXELS 2000000
#define NUM_CLUSTS 2000
#define NUM_EDGES  16000

// SoA accumulator: sums at [f*ST + c] (f=0..3), count at [4*ST + c].
// ST=2048 -> LDS bank = c%32, full 32-bank spread for random cluster ids.
#define ST   2048
#define ACCN (5 * ST)  // 10240 floats = 40 KiB

#define A_THREADS 1024
#define NSLICE (ACCN / 256)  // 40
#define RED_CH 64            // partials summed per reduce-block

__global__ __launch_bounds__(A_THREADS) void seg_accum(
        const float* __restrict__ data,
        const int* __restrict__ cids,
        float* __restrict__ part) {
    __shared__ float ls[ACCN];
    for (int o = threadIdx.x; o < ACCN; o += A_THREADS) ls[o] = 0.0f;
    __syncthreads();

    const int ngroups = NUM_VOXELS / 4;  // 4 voxels = 5 float4 + 1 int4 per iter
    for (int g = blockIdx.x * A_THREADS + threadIdx.x; g < ngroups;
         g += gridDim.x * A_THREADS) {
        const float4* dp = (const float4*)(data + 20ull * (unsigned)g);
        float4 q0 = dp[0];
        float4 q1 = dp[1];
        float4 q2 = dp[2];
        float4 q3 = dp[3];
        float4 q4 = dp[4];
        int4 c4 = *(const int4*)(cids + 4ull * (unsigned)g);

        // voxel 0: flat floats 1..4
        atomicAdd(&ls[0 * ST + c4.x], q0.y);
        atomicAdd(&ls[1 * ST + c4.x], q0.z);
        atomicAdd(&ls[2 * ST + c4.x], q0.w);
        atomicAdd(&ls[3 * ST + c4.x], q1.x);
        atomicAdd(&ls[4 * ST + c4.x], 1.0f);
        // voxel 1: flat floats 6..9
        atomicAdd(&ls[0 * ST + c4.y], q1.z);
        atomicAdd(&ls[1 * ST + c4.y], q1.w);
        atomicAdd(&ls[2 * ST + c4.y], q2.x);
        atomicAdd(&ls[3 * ST + c4.y], q2.y);
        atomicAdd(&ls[4 * ST + c4.y], 1.0f);
        // voxel 2: flat floats 11..14
        atomicAdd(&ls[0 * ST + c4.z], q2.w);
        atomicAdd(&ls[1 * ST + c4.z], q3.x);
        atomicAdd(&ls[2 * ST + c4.z], q3.y);
        atomicAdd(&ls[3 * ST + c4.z], q3.z);
        atomicAdd(&ls[4 * ST + c4.z], 1.0f);
        // voxel 3: flat floats 16..19
        atomicAdd(&ls[0 * ST + c4.w], q4.x);
        atomicAdd(&ls[1 * ST + c4.w], q4.y);
        atomicAdd(&ls[2 * ST + c4.w], q4.z);
        atomicAdd(&ls[3 * ST + c4.w], q4.w);
        atomicAdd(&ls[4 * ST + c4.w], 1.0f);
    }
    __syncthreads();

    // streaming, coalesced per-block partial dump (no global atomics)
    float* p = part + (size_t)blockIdx.x * ACCN;
    for (int o = threadIdx.x; o < ACCN; o += A_THREADS) p[o] = ls[o];
}

// fallback when ws is too small for partials: atomic flush into zeroed acc
__global__ __launch_bounds__(A_THREADS) void seg_accum_atomic(
        const float* __restrict__ data,
        const int* __restrict__ cids,
        float* __restrict__ acc) {
    __shared__ float ls[ACCN];
    for (int o = threadIdx.x; o < ACCN; o += A_THREADS) ls[o] = 0.0f;
    __syncthreads();
    const int ngroups = NUM_VOXELS / 4;
    for (int g = blockIdx.x * A_THREADS + threadIdx.x; g < ngroups;
         g += gridDim.x * A_THREADS) {
        const float4* dp = (const float4*)(data + 20ull * (unsigned)g);
        float4 q0 = dp[0], q1 = dp[1], q2 = dp[2], q3 = dp[3], q4 = dp[4];
        int4 c4 = *(const int4*)(cids + 4ull * (unsigned)g);
        atomicAdd(&ls[0 * ST + c4.x], q0.y);
        atomicAdd(&ls[1 * ST + c4.x], q0.z);
        atomicAdd(&ls[2 * ST + c4.x], q0.w);
        atomicAdd(&ls[3 * ST + c4.x], q1.x);
        atomicAdd(&ls[4 * ST + c4.x], 1.0f);
        atomicAdd(&ls[0 * ST + c4.y], q1.z);
        atomicAdd(&ls[1 * ST + c4.y], q1.w);
        atomicAdd(&ls[2 * ST + c4.y], q2.x);
        atomicAdd(&ls[3 * ST + c4.y], q2.y);
        atomicAdd(&ls[4 * ST + c4.y], 1.0f);
        atomicAdd(&ls[0 * ST + c4.z], q2.w);
        atomicAdd(&ls[1 * ST + c4.z], q3.x);
        atomicAdd(&ls[2 * ST + c4.z], q3.y);
        atomicAdd(&ls[3 * ST + c4.z], q3.z);
        atomicAdd(&ls[4 * ST + c4.z], 1.0f);
        atomicAdd(&ls[0 * ST + c4.w], q4.x);
        atomicAdd(&ls[1 * ST + c4.w], q4.y);
        atomicAdd(&ls[2 * ST + c4.w], q4.z);
        atomicAdd(&ls[3 * ST + c4.w], q4.w);
        atomicAdd(&ls[4 * ST + c4.w], 1.0f);
    }
    __syncthreads();
    for (int o = threadIdx.x; o < ACCN; o += A_THREADS) {
        float v = ls[o];
        if (v != 0.0f)
            __hip_atomic_fetch_add(&acc[o], v, __ATOMIC_RELAXED,
                                   __HIP_MEMORY_SCOPE_AGENT);
    }
}

// grid = dim3(NSLICE, nblocks / RED_CH); block = 256
__global__ __launch_bounds__(256) void seg_reduce(
        const float* __restrict__ part, float* __restrict__ acc) {
    const int i = blockIdx.x * 256 + threadIdx.x;
    const float* p = part + (size_t)blockIdx.y * RED_CH * ACCN + i;
    float s0 = 0.f, s1 = 0.f, s2 = 0.f, s3 = 0.f;
#pragma unroll
    for (int b = 0; b < RED_CH; b += 4) {
        s0 += p[(size_t)(b + 0) * ACCN];
        s1 += p[(size_t)(b + 1) * ACCN];
        s2 += p[(size_t)(b + 2) * ACCN];
        s3 += p[(size_t)(b + 3) * ACCN];
    }
    __hip_atomic_fetch_add(&acc[i], (s0 + s1) + (s2 + s3), __ATOMIC_RELAXED,
                           __HIP_MEMORY_SCOPE_AGENT);
}

#define E_BLOCKS 512
#define E_THREADS 256
#define E_WAVES (E_BLOCKS * (E_THREADS / 64))

__global__ __launch_bounds__(E_THREADS) void edge_mlp(
        const float* __restrict__ acc,
        const int* __restrict__ eidx,
        const float* __restrict__ W1, const float* __restrict__ b1,
        const float* __restrict__ W2, const float* __restrict__ b2,
        float* __restrict__ out) {
    __shared__ float sacc[ACCN];                 // 40 KiB staged accumulators
    __shared__ float hbuf[E_THREADS / 64][128];  // per-wave h exchange
    const int lane = threadIdx.x & 63;
    const int w = threadIdx.x >> 6;
    const int wg = blockIdx.x * (E_THREADS / 64) + w;

    float w1a[4], w1b[4];
#pragma unroll
    for (int c = 0; c < 4; ++c) {
        w1a[c] = W1[c * 128 + lane];
        w1b[c] = W1[c * 128 + 64 + lane];
    }
    const float b1a = b1[lane];
    const float b1b = b1[64 + lane];
    const float b2j = b2[lane];
    float w2c[128];  // W2 column `lane` in registers (coalesced, L2-resident)
#pragma unroll
    for (int k = 0; k < 128; ++k) w2c[k] = W2[k * 64 + lane];

    for (int o = threadIdx.x; o < ACCN; o += E_THREADS) sacc[o] = acc[o];
    __syncthreads();

    for (int e = wg; e < NUM_EDGES; e += E_WAVES) {
        const int e0 = eidx[e];
        const int e1 = eidx[NUM_EDGES + e];
        const float cnt = sacc[4 * ST + e0] + sacc[4 * ST + e1];
        const float rden = 1.0f / fmaxf(cnt, 1.0f);
        const float p0 = (sacc[0 * ST + e0] + sacc[0 * ST + e1]) * rden;
        const float p1 = (sacc[1 * ST + e0] + sacc[1 * ST + e1]) * rden;
        const float p2 = (sacc[2 * ST + e0] + sacc[2 * ST + e1]) * rden;
        const float p3 = (sacc[3 * ST + e0] + sacc[3 * ST + e1]) * rden;

        float ha = b1a + p0 * w1a[0] + p1 * w1a[1] + p2 * w1a[2] + p3 * w1a[3];
        float hb = b1b + p0 * w1b[0] + p1 * w1b[1] + p2 * w1b[2] + p3 * w1b[3];
        ha = fmaxf(ha, 0.0f);
        hb = fmaxf(hb, 0.0f);

        hbuf[w][lane] = ha;
        hbuf[w][64 + lane] = hb;

        float o0 = b2j;
#pragma unroll
        for (int k = 0; k < 128; k += 4) {
            float4 h4 = *(const float4*)&hbuf[w][k];  // broadcast read
            o0 += h4.x * w2c[k] + h4.y * w2c[k + 1] + h4.z * w2c[k + 2] +
                  h4.w * w2c[k + 3];
        }
        out[(size_t)e * 64 + lane] = o0;  // coalesced 256B per wave
    }
}

extern "C" void kernel_launch(void* const* d_in, const int* in_sizes, int n_in,
                              void* d_out, int out_size, void* d_ws, size_t ws_size,
                              hipStream_t stream) {
    const float* data = (const float*)d_in[0];
    const int* cids   = (const int*)d_in[1];
    const int* eidx   = (const int*)d_in[2];
    const float* W1   = (const float*)d_in[3];
    const float* b1   = (const float*)d_in[4];
    const float* W2   = (const float*)d_in[5];
    const float* b2   = (const float*)d_in[6];
    float* out = (float*)d_out;
    float* ws  = (float*)d_ws;

    // choose accumulation block count by available workspace
    int ab = 0;
    if (ws_size >= (size_t)(512 + 1) * ACCN * sizeof(float)) ab = 512;
    else if (ws_size >= (size_t)(256 + 1) * ACCN * sizeof(float)) ab = 256;

    if (ab > 0) {
        float* part = ws;
        float* acc = ws + (size_t)ab * ACCN;
        hipMemsetAsync(acc, 0, ACCN * sizeof(float), stream);
        seg_accum<<<ab, A_THREADS, 0, stream>>>(data, cids, part);
        seg_reduce<<<dim3(NSLICE, ab / RED_CH), 256, 0, stream>>>(part, acc);
        edge_mlp<<<E_BLOCKS, E_THREADS, 0, stream>>>(acc, eidx, W1, b1, W2, b2, out);
    } else {
        float* acc = ws;
        hipMemsetAsync(acc, 0, ACCN * sizeof(float), stream);
        seg_accum_atomic<<<256, A_THREADS, 0, stream>>>(data, cids, acc);
        edge_mlp<<<E_BLOCKS, E_THREADS, 0, stream>>>(acc, eidx, W1, b1, W2, b2, out);
    }
}

// Round 4
// 127.706 us; speedup vs baseline: 1.3786x; 1.3706x over previous
//
#include <hip/hip_runtime.h>

#define NUM_VOXELS 2000000
#define NUM_CLUSTS 2000
#define NUM_EDGES  16000

// SoA accumulator: sums at [f*ST + c] (f=0..3), count at [4*ST + c].
// ST=2048 -> LDS bank = c%32, full 32-bank spread for random cluster ids.
#define ST   2048
#define ACCN (5 * ST)  // 10240 ints = 40 KiB

// Fixed-point: int atomics (ds_add_u32) are ALWAYS native; float atomicAdd on
// LDS compiles to a CAS loop under default (IEEE-denormal) flags -> ~100x slow.
#define FSCALE 131072.0f          // 2^17
#define FINV   (1.0f / 131072.0f)

#define A_THREADS 1024
#define A_BLOCKS  512
#define NSLICE (ACCN / 256)  // 40
#define RED_CH 64            // partials summed per reduce-block

__device__ __forceinline__ int fxp(float v) {
    return __float2int_rn(v * FSCALE);
}

__global__ __launch_bounds__(A_THREADS) void seg_accum(
        const float* __restrict__ data,
        const int* __restrict__ cids,
        int* __restrict__ part) {
    __shared__ int ls[ACCN];
    for (int o = threadIdx.x; o < ACCN; o += A_THREADS) ls[o] = 0;
    __syncthreads();

    const int ngroups = NUM_VOXELS / 4;  // 4 voxels = 5 float4 + 1 int4 per iter
    for (int g = blockIdx.x * A_THREADS + threadIdx.x; g < ngroups;
         g += gridDim.x * A_THREADS) {
        const float4* dp = (const float4*)(data + 20ull * (unsigned)g);
        float4 q0 = dp[0];
        float4 q1 = dp[1];
        float4 q2 = dp[2];
        float4 q3 = dp[3];
        float4 q4 = dp[4];
        int4 c4 = *(const int4*)(cids + 4ull * (unsigned)g);

        // voxel 0: flat floats 1..4
        atomicAdd(&ls[0 * ST + c4.x], fxp(q0.y));
        atomicAdd(&ls[1 * ST + c4.x], fxp(q0.z));
        atomicAdd(&ls[2 * ST + c4.x], fxp(q0.w));
        atomicAdd(&ls[3 * ST + c4.x], fxp(q1.x));
        atomicAdd(&ls[4 * ST + c4.x], 1);
        // voxel 1: flat floats 6..9
        atomicAdd(&ls[0 * ST + c4.y], fxp(q1.z));
        atomicAdd(&ls[1 * ST + c4.y], fxp(q1.w));
        atomicAdd(&ls[2 * ST + c4.y], fxp(q2.x));
        atomicAdd(&ls[3 * ST + c4.y], fxp(q2.y));
        atomicAdd(&ls[4 * ST + c4.y], 1);
        // voxel 2: flat floats 11..14
        atomicAdd(&ls[0 * ST + c4.z], fxp(q2.w));
        atomicAdd(&ls[1 * ST + c4.z], fxp(q3.x));
        atomicAdd(&ls[2 * ST + c4.z], fxp(q3.y));
        atomicAdd(&ls[3 * ST + c4.z], fxp(q3.z));
        atomicAdd(&ls[4 * ST + c4.z], 1);
        // voxel 3: flat floats 16..19
        atomicAdd(&ls[0 * ST + c4.w], fxp(q4.x));
        atomicAdd(&ls[1 * ST + c4.w], fxp(q4.y));
        atomicAdd(&ls[2 * ST + c4.w], fxp(q4.z));
        atomicAdd(&ls[3 * ST + c4.w], fxp(q4.w));
        atomicAdd(&ls[4 * ST + c4.w], 1);
    }
    __syncthreads();

    // streaming, coalesced per-block partial dump (exact int, no atomics)
    int* p = part + (size_t)blockIdx.x * ACCN;
    for (int o = threadIdx.x; o < ACCN; o += A_THREADS) p[o] = ls[o];
}

// fallback (small ws): native global int atomics into memset acc
__global__ __launch_bounds__(A_THREADS) void seg_accum_atomic(
        const float* __restrict__ data,
        const int* __restrict__ cids,
        int* __restrict__ acc) {
    __shared__ int ls[ACCN];
    for (int o = threadIdx.x; o < ACCN; o += A_THREADS) ls[o] = 0;
    __syncthreads();
    const int ngroups = NUM_VOXELS / 4;
    for (int g = blockIdx.x * A_THREADS + threadIdx.x; g < ngroups;
         g += gridDim.x * A_THREADS) {
        const float4* dp = (const float4*)(data + 20ull * (unsigned)g);
        float4 q0 = dp[0], q1 = dp[1], q2 = dp[2], q3 = dp[3], q4 = dp[4];
        int4 c4 = *(const int4*)(cids + 4ull * (unsigned)g);
        atomicAdd(&ls[0 * ST + c4.x], fxp(q0.y));
        atomicAdd(&ls[1 * ST + c4.x], fxp(q0.z));
        atomicAdd(&ls[2 * ST + c4.x], fxp(q0.w));
        atomicAdd(&ls[3 * ST + c4.x], fxp(q1.x));
        atomicAdd(&ls[4 * ST + c4.x], 1);
        atomicAdd(&ls[0 * ST + c4.y], fxp(q1.z));
        atomicAdd(&ls[1 * ST + c4.y], fxp(q1.w));
        atomicAdd(&ls[2 * ST + c4.y], fxp(q2.x));
        atomicAdd(&ls[3 * ST + c4.y], fxp(q2.y));
        atomicAdd(&ls[4 * ST + c4.y], 1);
        atomicAdd(&ls[0 * ST + c4.z], fxp(q2.w));
        atomicAdd(&ls[1 * ST + c4.z], fxp(q3.x));
        atomicAdd(&ls[2 * ST + c4.z], fxp(q3.y));
        atomicAdd(&ls[3 * ST + c4.z], fxp(q3.z));
        atomicAdd(&ls[4 * ST + c4.z], 1);
        atomicAdd(&ls[0 * ST + c4.w], fxp(q4.x));
        atomicAdd(&ls[1 * ST + c4.w], fxp(q4.y));
        atomicAdd(&ls[2 * ST + c4.w], fxp(q4.z));
        atomicAdd(&ls[3 * ST + c4.w], fxp(q4.w));
        atomicAdd(&ls[4 * ST + c4.w], 1);
    }
    __syncthreads();
    for (int o = threadIdx.x; o < ACCN; o += A_THREADS) {
        int v = ls[o];
        if (v != 0) atomicAdd(&acc[o], v);  // native global_atomic_add_u32
    }
}

// grid = dim3(NSLICE, A_BLOCKS / RED_CH); block = 256. Exact int reduction,
// native int atomic finalize into memset acc.
__global__ __launch_bounds__(256) void seg_reduce(
        const int* __restrict__ part, int* __restrict__ acc) {
    const int i = blockIdx.x * 256 + threadIdx.x;
    const int* p = part + (size_t)blockIdx.y * RED_CH * ACCN + i;
    int s0 = 0, s1 = 0, s2 = 0, s3 = 0;
#pragma unroll
    for (int b = 0; b < RED_CH; b += 4) {
        s0 += p[(size_t)(b + 0) * ACCN];
        s1 += p[(size_t)(b + 1) * ACCN];
        s2 += p[(size_t)(b + 2) * ACCN];
        s3 += p[(size_t)(b + 3) * ACCN];
    }
    atomicAdd(&acc[i], (s0 + s1) + (s2 + s3));
}

#define E_BLOCKS 256
#define E_THREADS 256
#define E_WAVES (E_BLOCKS * (E_THREADS / 64))

__global__ __launch_bounds__(E_THREADS) void edge_mlp(
        const int* __restrict__ acc,
        const int* __restrict__ eidx,
        const float* __restrict__ W1, const float* __restrict__ b1,
        const float* __restrict__ W2, const float* __restrict__ b2,
        float* __restrict__ out) {
    __shared__ float sacc[ACCN];                 // 40 KiB staged accumulators
    __shared__ float hbuf[E_THREADS / 64][128];  // per-wave h exchange
    const int lane = threadIdx.x & 63;
    const int w = threadIdx.x >> 6;
    const int wg = blockIdx.x * (E_THREADS / 64) + w;

    float w1a[4], w1b[4];
#pragma unroll
    for (int c = 0; c < 4; ++c) {
        w1a[c] = W1[c * 128 + lane];
        w1b[c] = W1[c * 128 + 64 + lane];
    }
    const float b1a = b1[lane];
    const float b1b = b1[64 + lane];
    const float b2j = b2[lane];
    float w2c[128];  // W2 column `lane` in registers (coalesced, L2-resident)
#pragma unroll
    for (int k = 0; k < 128; ++k) w2c[k] = W2[k * 64 + lane];

    // stage + fixed-point -> float convert (branch is uniform per iteration:
    // boundary 4*ST=8192 is a multiple of E_THREADS)
    for (int o = threadIdx.x; o < ACCN; o += E_THREADS) {
        int v = acc[o];
        sacc[o] = (o < 4 * ST) ? (float)v * FINV : (float)v;
    }
    __syncthreads();

    for (int e = wg; e < NUM_EDGES; e += E_WAVES) {
        const int e0 = eidx[e];
        const int e1 = eidx[NUM_EDGES + e];
        const float cnt = sacc[4 * ST + e0] + sacc[4 * ST + e1];
        const float rden = 1.0f / fmaxf(cnt, 1.0f);
        const float p0 = (sacc[0 * ST + e0] + sacc[0 * ST + e1]) * rden;
        const float p1 = (sacc[1 * ST + e0] + sacc[1 * ST + e1]) * rden;
        const float p2 = (sacc[2 * ST + e0] + sacc[2 * ST + e1]) * rden;
        const float p3 = (sacc[3 * ST + e0] + sacc[3 * ST + e1]) * rden;

        float ha = b1a + p0 * w1a[0] + p1 * w1a[1] + p2 * w1a[2] + p3 * w1a[3];
        float hb = b1b + p0 * w1b[0] + p1 * w1b[1] + p2 * w1b[2] + p3 * w1b[3];
        ha = fmaxf(ha, 0.0f);
        hb = fmaxf(hb, 0.0f);

        hbuf[w][lane] = ha;
        hbuf[w][64 + lane] = hb;

        float o0 = b2j;
#pragma unroll
        for (int k = 0; k < 128; k += 4) {
            float4 h4 = *(const float4*)&hbuf[w][k];  // broadcast read
            o0 += h4.x * w2c[k] + h4.y * w2c[k + 1] + h4.z * w2c[k + 2] +
                  h4.w * w2c[k + 3];
        }
        out[(size_t)e * 64 + lane] = o0;  // coalesced 256B per wave
    }
}

extern "C" void kernel_launch(void* const* d_in, const int* in_sizes, int n_in,
                              void* d_out, int out_size, void* d_ws, size_t ws_size,
                              hipStream_t stream) {
    const float* data = (const float*)d_in[0];
    const int* cids   = (const int*)d_in[1];
    const int* eidx   = (const int*)d_in[2];
    const float* W1   = (const float*)d_in[3];
    const float* b1   = (const float*)d_in[4];
    const float* W2   = (const float*)d_in[5];
    const float* b2   = (const float*)d_in[6];
    float* out = (float*)d_out;
    int* ws = (int*)d_ws;

    if (ws_size >= (size_t)(A_BLOCKS + 1) * ACCN * sizeof(int)) {
        int* part = ws;
        int* acc = ws + (size_t)A_BLOCKS * ACCN;
        hipMemsetAsync(acc, 0, ACCN * sizeof(int), stream);
        seg_accum<<<A_BLOCKS, A_THREADS, 0, stream>>>(data, cids, part);
        seg_reduce<<<dim3(NSLICE, A_BLOCKS / RED_CH), 256, 0, stream>>>(part, acc);
        edge_mlp<<<E_BLOCKS, E_THREADS, 0, stream>>>(acc, eidx, W1, b1, W2, b2, out);
    } else {
        int* acc = ws;
        hipMemsetAsync(acc, 0, ACCN * sizeof(int), stream);
        seg_accum_atomic<<<A_BLOCKS, A_THREADS, 0, stream>>>(data, cids, acc);
        edge_mlp<<<E_BLOCKS, E_THREADS, 0, stream>>>(acc, eidx, W1, b1, W2, b2, out);
    }
}